// Round 6
// baseline (126.590 us; speedup 1.0000x reference)
//
#include <hip/hip_runtime.h>
#include <hip/hip_bf16.h>

#define D 128
#define TPB 8                          // 32-row tiles per block
#define NBUF 5                         // LDS ring buffers (depth-3 safe w/ 1 barrier)
#define TILE_BYTES (32 * D * 4)        // 16384
#define ROWS_PER_BLOCK (32 * TPB)      // 256 -> grid 512 = 2 blocks/CU (80KB LDS each)

typedef __attribute__((ext_vector_type(8))) short short8;
typedef __attribute__((ext_vector_type(4))) float float4_t;

typedef const __attribute__((address_space(1))) void g_void;
typedef __attribute__((address_space(3))) void l_void;

// ---------------------------------------------------------------------------
// Kernel 1: fold the 4 candidate ops into one combined matrix/bias.
// ---------------------------------------------------------------------------
__global__ void combine_kernel(const float* __restrict__ W,
                               const float* __restrict__ b,
                               const float* __restrict__ wts,
                               __hip_bfloat16* __restrict__ Wc,
                               float* __restrict__ bc) {
    int idx = blockIdx.x * blockDim.x + threadIdx.x;
    float w0 = wts[0], w1 = wts[1], w2 = wts[2], w3 = wts[3];
    if (idx < D * D) {
        float v = w0 * W[idx] + w1 * W[D * D + idx]
                + w2 * W[2 * D * D + idx] + w3 * W[3 * D * D + idx];
        Wc[idx] = __float2bfloat16(v);
    }
    if (idx < D) {
        bc[idx] = w0 * b[idx] + w1 * b[D + idx] + w2 * b[2 * D + idx] + w3 * b[3 * D + idx];
    }
}

__device__ __forceinline__ short8 cvt8_bf16(float4_t a, float4_t b) {
    union { short8 s; __hip_bfloat16 h[8]; } u;
    u.h[0] = __float2bfloat16(a[0]);
    u.h[1] = __float2bfloat16(a[1]);
    u.h[2] = __float2bfloat16(a[2]);
    u.h[3] = __float2bfloat16(a[3]);
    u.h[4] = __float2bfloat16(b[0]);
    u.h[5] = __float2bfloat16(b[1]);
    u.h[6] = __float2bfloat16(b[2]);
    u.h[7] = __float2bfloat16(b[3]);
    return u.s;
}

// ---------------------------------------------------------------------------
// Kernel 2: y[m][f] = sum_d x[m][d] * Wc[f][d] + bc[f]   (M = 131072)
//
// Session evidence: perf tracks sustained stage-ahead depth (R4 depth-2 =
// 35us; R5 depth-1 and all compiler-scheduled variants = 40-44us). This is
// R4's async global_load_lds pipeline DEEPENED: NBUF=5 ring (80 KB, still
// exactly 2 blocks/CU), depth-3 prefetch, and ONE barrier per step instead
// of two.
//
// Single-barrier safety (NBUF=5, stage-first step order): stage(T+3)
// writes buf (T+3)%5 == (T-2)%5, last read at step T-2. Any wave issuing
// stage(T+3) has passed barrier(T-1) .. barrier(T-2+1); every wave reaches
// barrier(T-1) only after its step-(T-2) ds_reads drained (lgkmcnt(0)
// precedes it in program order). Write-after-read separation holds with
// one barrier.
//
// vmcnt audit (in-order retirement; stage=4 gll/lane, stores=4/step;
// stage(T+k) issued at top of step T+k-3): at vwait of step T, ops younger
// than stage(T) = 4*(#stages issued after) + 4*(#store batches after):
// N = {12,16,20,24,24,20,16,12}. Never 0 mid-loop (T4 discipline).
//
// LDS swizzle both-sides (rule #21): linear gll dest; global source slot
// pre-XORed (slot ^ (row&7)); ds_read applies the same XOR. Zero
// conflicts (verified R3/R4: SQ_LDS_BANK_CONFLICT = 0).
// ---------------------------------------------------------------------------
__global__ __launch_bounds__(256, 1) void gemm_kernel(const float* __restrict__ x,
                                                      const __hip_bfloat16* __restrict__ Wc,
                                                      const float* __restrict__ bc,
                                                      float* __restrict__ y, int M) {
    __shared__ __align__(16) char Bs[NBUF * TILE_BYTES];   // 81920 B

    const int tid  = threadIdx.x;
    const int lane = tid & 63;
    const int wave = tid >> 6;
    const int r    = lane & 15;
    const int quad = lane >> 4;
    const int hb   = wave & 1;    // row-half of the 32-row tile
    const int ch   = wave >> 1;   // col-half (64 of 128 f-columns)

    const int row0 = blockIdx.x * ROWS_PER_BLOCK;
    if (row0 >= M) return;
    const float* xblk = x + (size_t)row0 * D;

    // ---- Wc fragments + bias -> registers FIRST (older than all stages:
    //      the step-0 vwait(12) drains them before first MFMA) ----
    short8 wf[4][4];
    #pragma unroll
    for (int f = 0; f < 4; f++)
        #pragma unroll
        for (int ks = 0; ks < 4; ks++)
            wf[f][ks] = *(const short8*)((const short*)Wc
                          + (ch * 64 + f * 16 + r) * D + ks * 32 + quad * 8);

    float4_t bias[4];
    #pragma unroll
    for (int f = 0; f < 4; f++)
        bias[f] = *(const float4_t*)(bc + ch * 64 + f * 16 + quad * 4);

    // ---- per-lane swizzled LDS read offsets (slot = ks*8 + quad*2 + h) ----
    int dsoff[4][2];
    #pragma unroll
    for (int ks = 0; ks < 4; ks++)
        #pragma unroll
        for (int h = 0; h < 2; h++)
            dsoff[ks][h] = (hb * 16 + r) * 512
                         + (((ks * 8 + quad * 2 + h) ^ (r & 7)) << 4);

    // stage one 32-row tile -> ring buffer: 4 gll x16B per thread, linear
    // dest (wave-uniform + lane*16), pre-swizzled global source.
#define STAGE(t) {                                                              \
        const char* tb = (const char*)(xblk + (t) * 32 * D);                    \
        char* db = Bs + ((t) % NBUF) * TILE_BYTES;                              \
        _Pragma("unroll")                                                       \
        for (int g = 0; g < 4; g++) {                                           \
            int R  = g * 8 + (tid >> 5);                                        \
            int sl = tid & 31;                                                  \
            const char* src = tb + R * 512 + ((sl ^ (R & 7)) << 4);             \
            __builtin_amdgcn_global_load_lds((g_void*)src,                      \
                (l_void*)(db + g * 4096 + (tid >> 6) * 1024), 16, 0, 0);        \
        }                                                                       \
    }

    // ---- prologue: depth-3 ----
    STAGE(0)
    STAGE(1)
    STAGE(2)

#define STEP(T, NW) {                                                           \
        if ((T) + 3 < TPB) STAGE((T) + 3)                                       \
        asm volatile("s_waitcnt vmcnt(%0)" :: "i"(NW) : "memory");              \
        __builtin_amdgcn_sched_barrier(0);                                      \
        __builtin_amdgcn_s_barrier();                                           \
        const char* buf = Bs + ((T) % NBUF) * TILE_BYTES;                       \
        short8 xf[4];                                                           \
        _Pragma("unroll")                                                       \
        for (int ks = 0; ks < 4; ks++) {                                        \
            float4_t a0 = *(const float4_t*)(buf + dsoff[ks][0]);               \
            float4_t a1 = *(const float4_t*)(buf + dsoff[ks][1]);               \
            xf[ks] = cvt8_bf16(a0, a1);                                         \
        }                                                                       \
        asm volatile("s_waitcnt lgkmcnt(0)" ::: "memory");                      \
        __builtin_amdgcn_sched_barrier(0);                                      \
        float4_t acc[4];                                                        \
        _Pragma("unroll")                                                       \
        for (int f = 0; f < 4; f++) acc[f] = bias[f];                           \
        _Pragma("unroll")                                                       \
        for (int ks = 0; ks < 4; ks++) {                                        \
            _Pragma("unroll")                                                   \
            for (int f = 0; f < 4; f++)                                         \
                acc[f] = __builtin_amdgcn_mfma_f32_16x16x32_bf16(               \
                    wf[f][ks], xf[ks], acc[f], 0, 0, 0);                        \
        }                                                                       \
        float* yp = y + (size_t)(row0 + (T) * 32 + hb * 16 + r) * D             \
                      + ch * 64 + quad * 4;                                     \
        _Pragma("unroll")                                                       \
        for (int f = 0; f < 4; f++)                                             \
            *(float4_t*)(yp + f * 16) = acc[f];                                 \
    }

    STEP(0, 12)
    STEP(1, 16)
    STEP(2, 20)
    STEP(3, 24)
    STEP(4, 24)
    STEP(5, 20)
    STEP(6, 16)
    STEP(7, 12)
#undef STEP
#undef STAGE
}

extern "C" void kernel_launch(void* const* d_in, const int* in_sizes, int n_in,
                              void* d_out, int out_size, void* d_ws, size_t ws_size,
                              hipStream_t stream) {
    const float* x   = (const float*)d_in[0];   // (B,S,D) fp32
    const float* W   = (const float*)d_in[1];   // (NOPS,D,D) fp32
    const float* b   = (const float*)d_in[2];   // (NOPS,D) fp32
    const float* wts = (const float*)d_in[3];   // (NOPS,) fp32
    float* y = (float*)d_out;

    __hip_bfloat16* Wc = (__hip_bfloat16*)d_ws;
    float* bc = (float*)((char*)d_ws + D * D * sizeof(__hip_bfloat16));

    combine_kernel<<<(D * D + 255) / 256, 256, 0, stream>>>(W, b, wts, Wc, bc);

    const int M = in_sizes[0] / D;  // B*S = 131072
    gemm_kernel<<<M / ROWS_PER_BLOCK, 256, 0, stream>>>(x, Wc, bc, y, M);
}

// Round 7
// 123.937 us; speedup vs baseline: 1.0214x; 1.0214x over previous
//
#include <hip/hip_runtime.h>
#include <hip/hip_bf16.h>

#define D 128
#define TPB 8                          // 16-row tiles per block
#define NBUF 3                         // LDS ring buffers (depth-2, 2 barriers: R4-proven)
#define TILE_BYTES (16 * D * 4)        // 8192
#define ROWS_PER_BLOCK (16 * TPB)      // 128 -> grid 1024 = 4 resident blocks/CU

typedef __attribute__((ext_vector_type(8))) short short8;
typedef __attribute__((ext_vector_type(4))) float float4_t;

typedef const __attribute__((address_space(1))) void g_void;
typedef __attribute__((address_space(3))) void l_void;

// ---------------------------------------------------------------------------
// Kernel 1: fold the 4 candidate ops into one combined matrix/bias.
// ---------------------------------------------------------------------------
__global__ void combine_kernel(const float* __restrict__ W,
                               const float* __restrict__ b,
                               const float* __restrict__ wts,
                               __hip_bfloat16* __restrict__ Wc,
                               float* __restrict__ bc) {
    int idx = blockIdx.x * blockDim.x + threadIdx.x;
    float w0 = wts[0], w1 = wts[1], w2 = wts[2], w3 = wts[3];
    if (idx < D * D) {
        float v = w0 * W[idx] + w1 * W[D * D + idx]
                + w2 * W[2 * D * D + idx] + w3 * W[3 * D * D + idx];
        Wc[idx] = __float2bfloat16(v);
    }
    if (idx < D) {
        bc[idx] = w0 * b[idx] + w1 * b[D + idx] + w2 * b[2 * D + idx] + w3 * b[3 * D + idx];
    }
}

__device__ __forceinline__ short8 cvt8_bf16(float4_t a, float4_t b) {
    union { short8 s; __hip_bfloat16 h[8]; } u;
    u.h[0] = __float2bfloat16(a[0]);
    u.h[1] = __float2bfloat16(a[1]);
    u.h[2] = __float2bfloat16(a[2]);
    u.h[3] = __float2bfloat16(a[3]);
    u.h[4] = __float2bfloat16(b[0]);
    u.h[5] = __float2bfloat16(b[1]);
    u.h[6] = __float2bfloat16(b[2]);
    u.h[7] = __float2bfloat16(b[3]);
    return u.s;
}

// ---------------------------------------------------------------------------
// Kernel 2: y[m][f] = sum_d x[m][d] * Wc[f][d] + bc[f]   (M = 131072)
//
// Session evidence (R2-R6): all structures land at 37-46us with every pipe
// idle — waves are duty-cycle-limited (latency-serial step chain, ~2
// blocks/CU = too few independent pipelines). This keeps R4's proven step
// (depth-2 prefetch, two barriers, counted vmcnt) and DOUBLES per-CU
// concurrency: 16-row tiles (8KB), NBUF=3 -> 24KB LDS/block, 128
// rows/block, grid 1024 = 4 resident blocks/CU (16 waves/CU, 4/SIMD).
// Each wave owns a col-QUARTER (32 cols): wf[2][4]=32 VGPR, acc[2].
//
// vmcnt audit (2 gll/stage/lane, 2 stores/step, STAGE(T+2) at step-T top):
// younger-than-stage(T) at step T's vwait:
//   T=0: S1+S2 = 4;  T=1: S2+st0+S3 = 6;  T=2..5: st(T-2)+S(T+1)+st(T-1)
//   +S(T+2) = 8;  T=6: st4+S7+st5 = 6;  T=7: st5+st6 = 4.
// Counted, never 0 mid-loop (T4 discipline).
//
// LDS swizzle both-sides (rule #21): linear gll dest; global source slot
// pre-XORed (slot ^ (row&7)); ds_read applies the same XOR. Zero
// conflicts (measured R3/R4/R6).
// ---------------------------------------------------------------------------
__global__ __launch_bounds__(256, 4) void gemm_kernel(const float* __restrict__ x,
                                                      const __hip_bfloat16* __restrict__ Wc,
                                                      const float* __restrict__ bc,
                                                      float* __restrict__ y, int M) {
    __shared__ __align__(16) char Bs[NBUF * TILE_BYTES];   // 24576 B

    const int tid  = threadIdx.x;
    const int lane = tid & 63;
    const int wave = tid >> 6;    // col-quarter 0..3 (32 f-cols each)
    const int r    = lane & 15;
    const int quad = lane >> 4;

    const int row0 = blockIdx.x * ROWS_PER_BLOCK;
    if (row0 >= M) return;
    const float* xblk = x + (size_t)row0 * D;

    // ---- Wc fragments + bias -> registers FIRST (older than all stages;
    //      step-0 vwait(4) drains them before first use) ----
    short8 wf[2][4];
    #pragma unroll
    for (int f = 0; f < 2; f++)
        #pragma unroll
        for (int ks = 0; ks < 4; ks++)
            wf[f][ks] = *(const short8*)((const short*)Wc
                          + (wave * 32 + f * 16 + r) * D + ks * 32 + quad * 8);

    float4_t bias[2];
    #pragma unroll
    for (int f = 0; f < 2; f++)
        bias[f] = *(const float4_t*)(bc + wave * 32 + f * 16 + quad * 4);

    // ---- per-lane swizzled LDS read offsets (slot = ks*8 + quad*2 + h) ----
    int dsoff[4][2];
    #pragma unroll
    for (int ks = 0; ks < 4; ks++)
        #pragma unroll
        for (int h = 0; h < 2; h++)
            dsoff[ks][h] = r * 512 + (((ks * 8 + quad * 2 + h) ^ (r & 7)) << 4);

    // stage one 16-row tile (8KB): 2 gll x16B per thread; linear dest
    // (wave-uniform + lane*16), pre-swizzled global source.
    // rows: R = g*8 + (tid>>5); dest row = (g*4096 + wave*1024 + lane*16)/512
    //     = g*8 + 2*wave + (lane>=32) == R for this wave's tid range.
#define STAGE(t) {                                                              \
        const char* tb = (const char*)(xblk + (t) * 16 * D);                    \
        char* db = Bs + ((t) % NBUF) * TILE_BYTES;                              \
        _Pragma("unroll")                                                       \
        for (int g = 0; g < 2; g++) {                                           \
            int R  = g * 8 + (tid >> 5);                                        \
            int sl = tid & 31;                                                  \
            const char* src = tb + R * 512 + ((sl ^ (R & 7)) << 4);             \
            __builtin_amdgcn_global_load_lds((g_void*)src,                      \
                (l_void*)(db + g * 4096 + (tid >> 6) * 1024), 16, 0, 0);        \
        }                                                                       \
    }

    // ---- prologue: depth-2 ----
    STAGE(0)
    STAGE(1)

#define STEP(T, NW) {                                                           \
        if ((T) + 2 < TPB) STAGE((T) + 2)                                       \
        asm volatile("s_waitcnt vmcnt(%0)" :: "i"(NW) : "memory");              \
        __builtin_amdgcn_sched_barrier(0);                                      \
        __builtin_amdgcn_s_barrier();                                           \
        const char* buf = Bs + ((T) % NBUF) * TILE_BYTES;                       \
        short8 xf[4];                                                           \
        _Pragma("unroll")                                                       \
        for (int ks = 0; ks < 4; ks++) {                                        \
            float4_t a0 = *(const float4_t*)(buf + dsoff[ks][0]);               \
            float4_t a1 = *(const float4_t*)(buf + dsoff[ks][1]);               \
            xf[ks] = cvt8_bf16(a0, a1);                                         \
        }                                                                       \
        asm volatile("s_waitcnt lgkmcnt(0)" ::: "memory");                      \
        __builtin_amdgcn_sched_barrier(0);                                      \
        __builtin_amdgcn_s_barrier();  /* buf rewritten from step T+1 on */     \
        float4_t acc[2];                                                        \
        _Pragma("unroll")                                                       \
        for (int f = 0; f < 2; f++) acc[f] = bias[f];                           \
        _Pragma("unroll")                                                       \
        for (int ks = 0; ks < 4; ks++) {                                        \
            _Pragma("unroll")                                                   \
            for (int f = 0; f < 2; f++)                                         \
                acc[f] = __builtin_amdgcn_mfma_f32_16x16x32_bf16(               \
                    wf[f][ks], xf[ks], acc[f], 0, 0, 0);                        \
        }                                                                       \
        float* yp = y + (size_t)(row0 + (T) * 16 + r) * D + wave * 32           \
                      + quad * 4;                                               \
        _Pragma("unroll")                                                       \
        for (int f = 0; f < 2; f++)                                             \
            *(float4_t*)(yp + f * 16) = acc[f];                                 \
    }

    STEP(0, 4)
    STEP(1, 6)
    STEP(2, 8)
    STEP(3, 8)
    STEP(4, 8)
    STEP(5, 8)
    STEP(6, 6)
    STEP(7, 4)
#undef STEP
#undef STAGE
}

extern "C" void kernel_launch(void* const* d_in, const int* in_sizes, int n_in,
                              void* d_out, int out_size, void* d_ws, size_t ws_size,
                              hipStream_t stream) {
    const float* x   = (const float*)d_in[0];   // (B,S,D) fp32
    const float* W   = (const float*)d_in[1];   // (NOPS,D,D) fp32
    const float* b   = (const float*)d_in[2];   // (NOPS,D) fp32
    const float* wts = (const float*)d_in[3];   // (NOPS,) fp32
    float* y = (float*)d_out;

    __hip_bfloat16* Wc = (__hip_bfloat16*)d_ws;
    float* bc = (float*)((char*)d_ws + D * D * sizeof(__hip_bfloat16));

    combine_kernel<<<(D * D + 255) / 256, 256, 0, stream>>>(W, b, wts, Wc, bc);

    const int M = in_sizes[0] / D;  // B*S = 131072
    gemm_kernel<<<M / ROWS_PER_BLOCK, 256, 0, stream>>>(x, Wc, bc, y, M);
}